// Round 6
// baseline (4420.204 us; speedup 1.0000x reference)
//
#include <hip/hip_runtime.h>
#include <hip/hip_bf16.h>

#define TT 2048
typedef unsigned int uint32;
typedef unsigned long long uint64;

// ---- d_ws layout ----
// WREG : uint32 [4][88][512]                 offset 0        (720896 B)
// exA  : uint64 [2][64][4][256] {f32,tag}    offset 720896 B (1048576 B)
#define WREG_N   (4 * 88 * 512)          // 180224 dwords
#define EXA_N    (2 * 64 * 4 * 256)      // 131072 qwords

__device__ __forceinline__ float lo16(uint32 u) { return __uint_as_float(u << 16); }
__device__ __forceinline__ float hi16(uint32 u) { return __uint_as_float(u & 0xffff0000u); }

__device__ __forceinline__ uint32 packbf(float lo, float hi)
{
    __hip_bfloat16 a = __float2bfloat16(lo), b = __float2bfloat16(hi);
    unsigned short ua = *reinterpret_cast<unsigned short*>(&a);
    unsigned short ub = *reinterpret_cast<unsigned short*>(&b);
    return (uint32)ua | ((uint32)ub << 16);
}

// cat k-slice for gang member g: [x[128g..+128) | s[64g..+64) | I[32g..+32)]
__device__ __forceinline__ float getA(const float* W_ih, const float* W_hh,
                                      int g, int j, int k)
{
    if (k < 128) return W_ih[j * 640 + 128 * g + k];
    if (k < 192) return W_hh[j * 256 + 64 * g + (k - 128)];
    return W_ih[j * 640 + 512 + 32 * g + (k - 192)];
}

// Weight layouts (per member g, per thread tid in [0,512)):
//  A: j = tid>>1, h = tid&1. Pair slot i<56: k0 = 112*h + 2*i (k within slice).
//  B: n = 128g + (tid>>2), kq = tid&3. Slot i in [56,88): p=i-56, s=p>>1, q=p&1,
//     blk = (s + 2*kq) & 15  (bank-rotation), k0 = 64*kq + 4*blk + 2*q.
__global__ void prep_kernel(const float* __restrict__ W_ih,
                            const float* __restrict__ W_hh,
                            const float* __restrict__ W_out,
                            uint32* __restrict__ WREG,
                            uint64* __restrict__ exA)
{
    int idx = blockIdx.x * blockDim.x + threadIdx.x;
    if (idx < WREG_N) {
        int tid = idx & 511;
        int q   = idx >> 9;      // g*88 + i
        int g   = q / 88;
        int i   = q % 88;
        float lo, hi;
        if (i < 56) {
            int j = tid >> 1, h = tid & 1;
            int k0 = 112 * h + 2 * i;
            lo = getA(W_ih, W_hh, g, j, k0);
            hi = getA(W_ih, W_hh, g, j, k0 + 1);
        } else {
            int p  = i - 56;
            int s  = p >> 1, qq = p & 1;
            int kq = tid & 3;
            int n  = 128 * g + (tid >> 2);
            int blk = (s + 2 * kq) & 15;
            int k0  = 64 * kq + 4 * blk + 2 * qq;
            lo = W_out[n * 256 + k0];
            hi = W_out[n * 256 + k0 + 1];
        }
        WREG[idx] = packbf(lo, hi);
    } else if (idx < WREG_N + EXA_N) {
        exA[idx - WREG_N] = 0ULL;   // tags must start at 0 (ws is 0xAA-poisoned)
    }
}

// LDS-only barrier: does NOT drain vmcnt (global ops stay in flight).
__device__ __forceinline__ void bar_lds()
{
    asm volatile("s_waitcnt lgkmcnt(0)" ::: "memory");
    __builtin_amdgcn_s_barrier();
    asm volatile("" ::: "memory");
}

__global__ __launch_bounds__(512)
void scan_kernel(const float* __restrict__ I,
                 const float* __restrict__ b_ih, const float* __restrict__ b_hh,
                 const float* __restrict__ b_out, const float* __restrict__ A,
                 const uint32* __restrict__ WREG,
                 uint64* exA,
                 float* __restrict__ out)
{
    // act state, parity double-buffered: [x 0:128 | s 128:192 | I 192:224] floats
    __shared__ float4 aloc4[2][56];
    __shared__ float  sful[256];    // full s (redundant per WG)

    const int tid = threadIdx.x;
    const int bid = blockIdx.x;
    const int b   = bid & 63;     // batch element
    const int g   = bid >> 6;     // gang member

    // ---- weights -> VGPR (static-indexed, fully unrolled) ----
    uint32 wA[56], wB[32];
    const uint32* wsrc = WREG + (g * 88) * 512 + tid;
    #pragma unroll
    for (int i = 0; i < 56; ++i) wA[i] = wsrc[i * 512];
    #pragma unroll
    for (int i = 0; i < 32; ++i) wB[i] = wsrc[(56 + i) * 512];

    const int h  = tid & 1;       // A k-half within lane pair
    const int jA = tid >> 1;      // A output row (per lane pair)
    const int kq = tid & 3;       // B k-quarter within lane quad
    const int nB = tid >> 2;      // B output row (per lane quad)

    const float bs   = ((tid & 1) == 0) ? (b_ih[jA] + b_hh[jA]) : 0.f;
    const float bo_r = ((tid & 3) == 0) ? b_out[128 * g + nB] : 0.f;
    const float Av_r = ((tid & 3) == 0) ? A[128 * g + nB] : 0.f;

    const size_t iBase   = (size_t)b * TT * 128 + 32 * g;
    const size_t outBase = (size_t)b * TT * 512 + 128 * g;

    {   // init state buffer 0: x=0, s=0, I(0)
        float* a0 = (float*)&aloc4[0][0];
        if (tid < 192) a0[tid] = 0.f;
        else if (tid < 224) a0[tid] = I[iBase + (tid - 192)];
    }
    __syncthreads();

    for (int t = 0; t < TT; ++t) {
        const int par = t & 1;
        const float4* rd = aloc4[par];
        float*        wr = (float*)aloc4[par ^ 1];

        // issue I(t+1) prefetch early; latency hides under the whole step
        float iv = 0.f;
        if (tid < 32) {
            int tl = (t + 1 < TT) ? (t + 1) : t;
            iv = I[iBase + (size_t)tl * 128 + tid];
        }

        // ---- phase A: pre[jA] partial; lane pair covers the 224-k slice ----
        float a0 = 0.f, a1 = 0.f;
        #pragma unroll
        for (int i = 0; i < 28; ++i) {
            float4 av = rd[28 * h + i];             // 2 addrs/lane-pair: conflict-free
            uint32 w0 = wA[2 * i], w1 = wA[2 * i + 1];
            a0 = fmaf(av.x, lo16(w0), a0);
            a1 = fmaf(av.y, hi16(w0), a1);
            a0 = fmaf(av.z, lo16(w1), a0);
            a1 = fmaf(av.w, hi16(w1), a1);
        }
        float accA = a0 + a1;
        accA += __shfl_xor(accA, 1);                // h0 + h1 -> full slice partial

        const uint32 tgt = (uint32)(t + 1);
        uint64* ex = exA + (size_t)(par * 64 + b) * (4 * 256);

        if ((tid & 1) == 0) {
            // tagged store issues IMMEDIATELY (no barrier, no LDS roundtrip)
            uint64 u = ((uint64)tgt << 32) | (uint64)__float_as_uint(accA);
            __hip_atomic_store(ex + g * 256 + jA, u,
                               __ATOMIC_RELAXED, __HIP_MEMORY_SCOPE_AGENT);

            // poll peers' payload words; fixed-order sum for determinism
            float v0 = 0.f, v1 = 0.f, v2 = 0.f;
            uint32 got = 0;
            const int g1 = (g + 1) & 3, g2 = (g + 2) & 3, g3 = (g + 3) & 3;
            do {
                if (!(got & 1u)) {
                    uint64 u1 = __hip_atomic_load(ex + g1 * 256 + jA,
                                                  __ATOMIC_RELAXED, __HIP_MEMORY_SCOPE_AGENT);
                    if ((uint32)(u1 >> 32) == tgt) { v0 = __uint_as_float((uint32)u1); got |= 1u; }
                }
                if (!(got & 2u)) {
                    uint64 u2 = __hip_atomic_load(ex + g2 * 256 + jA,
                                                  __ATOMIC_RELAXED, __HIP_MEMORY_SCOPE_AGENT);
                    if ((uint32)(u2 >> 32) == tgt) { v1 = __uint_as_float((uint32)u2); got |= 2u; }
                }
                if (!(got & 4u)) {
                    uint64 u3 = __hip_atomic_load(ex + g3 * 256 + jA,
                                                  __ATOMIC_RELAXED, __HIP_MEMORY_SCOPE_AGENT);
                    if ((uint32)(u3 >> 32) == tgt) { v2 = __uint_as_float((uint32)u3); got |= 4u; }
                }
            } while (got != 7u);

            float pre = accA + bs + v0 + v1 + v2;
            // tanh(x) = 1 - 2/(exp(2x)+1): exact identity, branch-free
            float e  = __expf(2.f * pre);
            float sn = 1.f - 2.f / (e + 1.f);
            sful[jA] = sn;
            int d = jA - 64 * g;
            if (d >= 0 && d < 64) wr[128 + d] = sn;  // own s-quarter for next A
        }
        bar_lds();                                  // (1) s ready

        // ---- phase B: f[nB]; lane quad covers k=256 (rotated blocks) ----
        const float4* s4 = (const float4*)sful;
        float c0 = 0.f, c1 = 0.f;
        #pragma unroll
        for (int s2 = 0; s2 < 16; ++s2) {
            int blk = (s2 + 2 * kq) & 15;           // bank rotation across quads
            float4 sv = s4[16 * kq + blk];
            uint32 w0 = wB[2 * s2], w1 = wB[2 * s2 + 1];
            c0 = fmaf(sv.x, lo16(w0), c0);
            c1 = fmaf(sv.y, hi16(w0), c1);
            c0 = fmaf(sv.z, lo16(w1), c0);
            c1 = fmaf(sv.w, hi16(w1), c1);
        }
        float f = c0 + c1;
        f += __shfl_xor(f, 1);
        f += __shfl_xor(f, 2);                      // full k-sum at all quad lanes

        if ((tid & 3) == 0) {
            float ff = fmaxf(f + bo_r, 0.f);
            float xo = ((const float*)rd)[nB];
            float xn = (xo + 0.1f * ff * Av_r) / (1.1f + 0.1f * ff);
            wr[nB] = xn;                            // own x-quarter for next A
            out[outBase + (size_t)t * 512 + nB] = xn;
        }
        if (tid < 32) wr[192 + tid] = iv;           // stage I(t+1)
        bar_lds();                                  // (2) state ready for next A
    }
}

extern "C" void kernel_launch(void* const* d_in, const int* in_sizes, int n_in,
                              void* d_out, int out_size, void* d_ws, size_t ws_size,
                              hipStream_t stream)
{
    const float* I     = (const float*)d_in[0];
    const float* W_ih  = (const float*)d_in[1];
    const float* W_hh  = (const float*)d_in[2];
    const float* b_ih  = (const float*)d_in[3];
    const float* b_hh  = (const float*)d_in[4];
    const float* W_out = (const float*)d_in[5];
    const float* b_out = (const float*)d_in[6];
    const float* A     = (const float*)d_in[7];

    uint32* WREG = (uint32*)d_ws;
    uint64* exA  = (uint64*)((uint32*)d_ws + WREG_N);

    const int total = WREG_N + EXA_N;
    prep_kernel<<<(total + 1023) / 1024, 1024, 0, stream>>>(W_ih, W_hh, W_out, WREG, exA);
    scan_kernel<<<256, 512, 0, stream>>>(I, b_ih, b_hh, b_out, A,
                                         WREG, exA, (float*)d_out);
}